// Round 3
// baseline (484.217 us; speedup 1.0000x reference)
//
#include <hip/hip_runtime.h>

// IndRNN, 2 layers, diagonal recurrence: h[t] = relu(x[t] + w*h[t-1]) per layer.
// x: [T=2048, B=32, H=512] fp32.
//
// R5 = R4 resubmit (previous bench died to container infra failure, not a
// kernel verdict; audit found no hang/fault path: no barriers, no LDS, all
// accesses bounds-guarded, uniform branches only).
//
// Design (vs R3): attack memory-level parallelism, not per-wave pipelining.
// R2 (deep reg pipeline) and R3 (producer/consumer LDS ring) both hit the same
// ~100 cy/element wall at 1-2 waves/CU -> the wall is per-CU in-flight bytes
// (inflight/latency), not FIFO structure. Fix: 4x the wave count.
//   - 1024 blocks x 64 threads, 16 chains per wave -> 4 waves/CU.
//   - Lane groups j=lane>>4 cover 4 consecutive timesteps of the SAME 16 chains:
//     one global_load_dword = 4 x 64B segments = 256 B/instr (same coalescing
//     as before, 4x fewer chains per wave).
//   - 4-way __shfl transpose broadcasts the quad; all 4 groups REDUNDANTLY
//     compute the 4-step recurrence (identical inputs -> identical h, zero
//     divergence), so lane j*16+i already holds h2[t0+j][chain i] and the
//     256 B store needs no shuffle-back.
//   - 16-quad register pipeline (static indices via unroll): ~16 loads + ~16
//     stores outstanding = vmcnt ~32, safely under the 6-bit cap; the compiler
//     inserts exact counted waits.

#define TSTEPS 2048
#define BATCH  32
#define HID    512
#define BH     (BATCH * HID)    /* 16384 chains */
#define CPB    16               /* chains per block (= per wave) */
#define QT     4                /* timesteps per quad (lane groups) */
#define NQ     (TSTEPS / QT)    /* 512 quads */
#define P      16               /* pipeline depth in quads (NQ % P == 0) */

__global__ __launch_bounds__(64, 1) void indrnn_tq_kernel(
    const float* __restrict__ x,
    const float* __restrict__ w_hh,
    const float* __restrict__ h0,
    float* __restrict__ out) {
  const int lane  = threadIdx.x;       // 0..63
  const int i     = lane & 15;         // chain within block
  const int j     = lane >> 4;         // timestep within quad
  const int cbase = blockIdx.x * CPB;
  const int c     = cbase + i;         // this lane's chain
  const int hid   = c & (HID - 1);

  const float w1 = w_hh[hid];
  const float w2 = w_hh[HID + hid];
  float h1 = h0[c];                    // identical across the 4 lane groups
  float h2 = h0[BH + c];

  // Lane's element within a quad: timestep j, chain c. Lanes 0..15 cover a
  // contiguous 64 B chain segment; the 4 groups sit 64 KB apart (4 segments
  // per 256 B instruction).
  const size_t goff = (size_t)j * BH + c;
  const float* xp = x + goff;
  float*       op = out + goff;

  // Register pipeline: P quads in flight.
  float buf[P];
#pragma unroll
  for (int q = 0; q < P; ++q)
    buf[q] = xp[(size_t)q * QT * BH];

  for (int qq = 0; qq < NQ; qq += P) {
#pragma unroll
    for (int d = 0; d < P; ++d) {
      const int q  = qq + d;
      const float xv = buf[d];         // consume before overwrite
      const int pq = q + P;
      if (pq < NQ)                     // uniform scalar branch
        buf[d] = xp[(size_t)pq * QT * BH];

      // Transpose-broadcast: xu = x[t0+u][c]; identical across lane groups.
      float sval = 0.0f;
#pragma unroll
      for (int u = 0; u < QT; ++u) {
        const float xu = __shfl(xv, u * 16 + i, 64);
        h1 = fmaxf(fmaf(w1, h1, xu), 0.0f);
        h2 = fmaxf(fmaf(w2, h2, h1), 0.0f);
        if (u == j) sval = h2;         // per-lane cndmask, no divergence
      }
      op[(size_t)q * QT * BH] = sval;  // 256 B/instr, fire-and-forget
    }
  }
}

extern "C" void kernel_launch(void* const* d_in, const int* in_sizes, int n_in,
                              void* d_out, int out_size, void* d_ws, size_t ws_size,
                              hipStream_t stream) {
  const float* x    = (const float*)d_in[0];
  const float* w_hh = (const float*)d_in[1];
  const float* h0   = (const float*)d_in[2];
  float* out        = (float*)d_out;

  dim3 grid(BH / CPB);   // 1024 blocks -> 4 waves/CU
  dim3 block(64);
  hipLaunchKernelGGL(indrnn_tq_kernel, grid, block, 0, stream,
                     x, w_hh, h0, out);
}

// Round 4
// 234.053 us; speedup vs baseline: 2.0688x; 2.0688x over previous
//
#include <hip/hip_runtime.h>

// IndRNN, 2 layers, diagonal recurrence: h[t] = relu(x[t] + w*h[t-1]) per layer.
// x: [T=2048, B=32, H=512] fp32. 16384 chains -> 256 blocks x 64 chains.
//
// R6 change: multi-producer DMA. Evidence so far:
//   R2 (reg pipe, 1 wave)   : 88 us, 2.25 TB/s, 256B-contiguous requests
//   R3 (1 producer + cons)  : 86 us, 2.35 TB/s, 256B-contiguous requests
//   R4 (4 waves, 64B quads) : 333 us, 0.81 TB/s, FETCH doubled
// R4 shows shrinking request granularity to 64B is a 4x loss; R2==R3 shows one
// load-issuing wave saturates at ~8-16KB in flight (per-wave outstanding-VMEM
// cap ~32 reqs), which at loaded HBM latency pins the chip at ~2.3 TB/s.
// Fix: FOUR producer waves (each with its own outstanding budget) + 1 consumer,
// keeping the 256B-contiguous pattern. 8-slot x 8KB LDS ring (64 KB), 7-phase
// lookahead: ~64 KB of loads in flight per CU (8x R3). Producer k owns phases
// p % 4 == k; counted vmcnt(8) waits (never 0 until its tail). Consumer's FIFO
// holds only fire-and-forget stores. Raw s_barrier (no vmcnt(0) drain) +
// sched_barrier pins (rule 18).

#define TSTEPS  2048
#define BATCH   32
#define HID     512
#define BH      (BATCH * HID)          /* 16384 chains */
#define PHASE_T 32                     /* timesteps per phase */
#define NPHASE  (TSTEPS / PHASE_T)     /* 64 */
#define NSLOT   8                      /* ring slots (power of 2) */
#define SLOT_FLOATS (PHASE_T * 64)     /* 2048 floats = 8 KiB */
#define SLOT_BYTES  (SLOT_FLOATS * 4)
#define LPP     (PHASE_T / 4)          /* 8 x 1KiB global_load_lds per phase */
#define NPROD   4

typedef __attribute__((address_space(1))) const void* gas_cvp;
typedef __attribute__((address_space(3))) void*       las_vp;

// One ISSUE moves one 8KB phase: 8 instrs x (64 lanes x 16B). Lane l = j*16+i
// sources x[t0 + m*4 + j, cbase + 4i .. 4i+3] (four full 256B rows per instr);
// LDS dest is linear (base + l*16), yielding [t][chain] layout, t-stride 256B.
#define ISSUE(q)                                                              \
  do {                                                                        \
    char* lb_ = (char*)lds + ((q) & (NSLOT - 1)) * SLOT_BYTES;                \
    const float* gq_ = gp + (size_t)(q) * PHASE_T * BH;                       \
    _Pragma("unroll")                                                         \
    for (int m_ = 0; m_ < LPP; ++m_) {                                        \
      __builtin_amdgcn_global_load_lds((gas_cvp)(gq_ + (size_t)m_ * 4 * BH),  \
                                       (las_vp)(lb_ + m_ * 1024), 16, 0, 0);  \
    }                                                                         \
  } while (0)

__global__ __launch_bounds__(320, 1) void indrnn_mp_kernel(
    const float* __restrict__ x,
    const float* __restrict__ w_hh,
    const float* __restrict__ h0,
    float* __restrict__ out) {
  __shared__ float lds[NSLOT * SLOT_FLOATS];   // 64 KiB ring

  const int tid   = threadIdx.x;
  const int wave  = tid >> 6;
  const int lane  = tid & 63;
  const int cbase = blockIdx.x * 64;

  if (wave < NPROD) {
    // ---------------- producer k: pure DMA, owns phases p%4==k -------------
    const int k = wave;
    const int j = lane >> 4;                   // row within 4-row chunk
    const int i = lane & 15;                   // 16B piece within 256B row
    const float* gp = x + cbase + (size_t)j * BH + i * 4;

    // Prologue: my first two batches (phases k and k+4). Slots 0..7 are empty.
    ISSUE(k);
    ISSUE(k + 4);

    for (int p = 0; p < NPHASE; ++p) {
      if ((p & 3) == k) {
        // Barrier B_p releases my phase p: guarantee it landed. Outstanding
        // here: {p, p+4} -> counted wait, only the tail drains to 0.
        __builtin_amdgcn_sched_barrier(0);
        if (p + 4 < NPHASE) asm volatile("s_waitcnt vmcnt(8)" ::: "memory");
        else                asm volatile("s_waitcnt vmcnt(0)" ::: "memory");
      }
      __builtin_amdgcn_s_barrier();            // B_p: phase p released
      __builtin_amdgcn_sched_barrier(0);
      // Slot (p+7)&7 held phase p-1, consumed before B_p -> safe to refill.
      const int q = p + 7;
      if (q >= 8 && q < NPHASE && (q & 3) == k) ISSUE(q);
    }
  } else {
    // ---------------- consumer: serial recurrence over 64 chains -----------
    const int c   = cbase + lane;
    const int hid = c & (HID - 1);
    const float w1 = w_hh[hid];
    const float w2 = w_hh[HID + hid];
    float h1 = h0[c];
    float h2 = h0[BH + c];
    float* op = out + c;

    for (int p = 0; p < NPHASE; ++p) {
      __builtin_amdgcn_s_barrier();            // B_p: phase p resident
      __builtin_amdgcn_sched_barrier(0);       // keep ds_reads after barrier
      const float* lb = lds + (p & (NSLOT - 1)) * SLOT_FLOATS + lane;
      float* ob = op + (size_t)p * PHASE_T * BH;
#pragma unroll
      for (int u = 0; u < PHASE_T; ++u) {
        const float xv = lb[u * 64];           // ds_read_b32, 2 lanes/bank: free
        h1 = fmaxf(fmaf(w1, h1, xv), 0.0f);
        h2 = fmaxf(fmaf(w2, h2, h1), 0.0f);
        ob[(size_t)u * BH] = h2;               // fire-and-forget store
      }
      __builtin_amdgcn_sched_barrier(0);       // keep reads before next barrier
    }
  }
}

extern "C" void kernel_launch(void* const* d_in, const int* in_sizes, int n_in,
                              void* d_out, int out_size, void* d_ws, size_t ws_size,
                              hipStream_t stream) {
  const float* x    = (const float*)d_in[0];
  const float* w_hh = (const float*)d_in[1];
  const float* h0   = (const float*)d_in[2];
  float* out        = (float*)d_out;

  dim3 grid(BH / 64);   // 256 blocks = 1 per CU
  dim3 block(320);      // waves 0-3: DMA producers; wave 4: consumer
  hipLaunchKernelGGL(indrnn_mp_kernel, grid, block, 0, stream,
                     x, w_hh, h0, out);
}

// Round 5
// 231.867 us; speedup vs baseline: 2.0883x; 1.0094x over previous
//
#include <hip/hip_runtime.h>

// IndRNN, 2 layers, diagonal recurrence: h[t] = relu(x[t] + w*h[t-1]) per layer.
// x: [T=2048, B=32, H=512] fp32. 16384 chains -> 256 blocks x 64 chains.
//
// R7 change: decouple the STORE path. Evidence: R2 (reg pipe), R3 (1 DMA
// producer), R6 (4 DMA producers, 64KB loads in flight) all = ~85us / 2.35TB/s
// -> load-side microstructure is irrelevant; the never-varied common factor is
// the store stream: a single serially-paced wave issuing 4B/lane (256B/instr)
// stores interleaved with the recurrence. Writes run at exactly 1 store/100cy
// = the kernel's pace.
// New structure (4 waves/block, 256 blocks = 1 block/CU):
//   wave 0: DMA producer, global_load_lds 16B -> x-ring (4 x 8KB), 3 phases
//           ahead, counted vmcnt (never 0 until tail).
//   wave 1: compute. Per phase: 32 x { ds_read_b32 x, 4 VALU, ds_write_b32 h2 }
//           -- touches ONLY LDS, never global. lgkmcnt(0) before each barrier.
//   waves 2,3: writers. Drain out-ring phase p-1 while compute fills phase p:
//           ds_read_b128 + global float4 stores (16B/lane, 1KB/instr), vmcnt
//           backpressure lands on writer waves only, never on the recurrence.
// Ring layout [t][chain] (t-stride 256B): compute's b32 reads/writes are
// 2 lanes/bank = free; writer 1KB b128 reads are the irreducible 8 words/bank.

#define TSTEPS  2048
#define BATCH   32
#define HID     512
#define BH      (BATCH * HID)          /* 16384 chains */
#define PHASE_T 32                     /* timesteps per phase */
#define NPHASE  (TSTEPS / PHASE_T)     /* 64 */
#define SLOT_FLOATS (PHASE_T * 64)     /* 2048 floats = 8 KiB */
#define SLOT_BYTES  (SLOT_FLOATS * 4)
#define LPP     (PHASE_T / 4)          /* 8 x 1KiB global_load_lds per phase */

typedef __attribute__((address_space(1))) const void* gas_cvp;
typedef __attribute__((address_space(3))) void*       las_vp;

// One ISSUE moves one 8KB x-phase: 8 instrs x (64 lanes x 16B). Lane l=j*16+i
// sources x[t0 + m*4 + j, cbase + 4i..4i+3] (four 256B rows per instr); LDS
// dest is linear (base + l*16) -> [t][chain] layout, t-stride 256B.
#define ISSUE(q)                                                              \
  do {                                                                        \
    char* lb_ = (char*)ldsx + ((q) & 3) * SLOT_BYTES;                         \
    const float* gq_ = gp + (size_t)(q) * PHASE_T * BH;                       \
    _Pragma("unroll")                                                         \
    for (int m_ = 0; m_ < LPP; ++m_) {                                        \
      __builtin_amdgcn_global_load_lds((gas_cvp)(gq_ + (size_t)m_ * 4 * BH),  \
                                       (las_vp)(lb_ + m_ * 1024), 16, 0, 0);  \
    }                                                                         \
  } while (0)

__global__ __launch_bounds__(256, 1) void indrnn_sw_kernel(
    const float* __restrict__ x,
    const float* __restrict__ w_hh,
    const float* __restrict__ h0,
    float* __restrict__ out) {
  __shared__ float ldsx[4 * SLOT_FLOATS];      // 32 KiB x ring
  __shared__ float ldso[4 * SLOT_FLOATS];      // 32 KiB h2 ring

  const int tid   = threadIdx.x;
  const int wave  = tid >> 6;
  const int lane  = tid & 63;
  const int cbase = blockIdx.x * 64;

  if (wave == 0) {
    // ---------------- producer: pure DMA ----------------
    const int j = lane >> 4;
    const int i = lane & 15;
    const float* gp = x + cbase + (size_t)j * BH + i * 4;

    ISSUE(0); ISSUE(1); ISSUE(2);              // 24 loads in flight
    __builtin_amdgcn_sched_barrier(0);
    asm volatile("s_waitcnt vmcnt(16)" ::: "memory");   // phase 0 resident

    for (int p = 0; p < NPHASE; ++p) {
      __builtin_amdgcn_s_barrier();            // B_p
      __builtin_amdgcn_sched_barrier(0);
      if (p + 3 < NPHASE) ISSUE(p + 3);        // slot (p-1)&3, freed at B_p
      __builtin_amdgcn_sched_barrier(0);
      // Phase p+1 must be resident before B_{p+1}.
      if (p + 3 < NPHASE)      asm volatile("s_waitcnt vmcnt(16)" ::: "memory");
      else if (p + 2 < NPHASE) asm volatile("s_waitcnt vmcnt(8)"  ::: "memory");
      else                     asm volatile("s_waitcnt vmcnt(0)"  ::: "memory");
    }
    __builtin_amdgcn_s_barrier();              // final
  } else if (wave == 1) {
    // ---------------- compute: LDS-only serial recurrence ----------------
    const int c   = cbase + lane;
    const int hid = c & (HID - 1);
    const float w1 = w_hh[hid];
    const float w2 = w_hh[HID + hid];
    float h1 = h0[c];
    float h2 = h0[BH + c];

    for (int p = 0; p < NPHASE; ++p) {
      __builtin_amdgcn_s_barrier();            // B_p: x[p] resident, out slot free
      __builtin_amdgcn_sched_barrier(0);
      const float* xb = ldsx + (p & 3) * SLOT_FLOATS + lane;
      float*       ob = ldso + (p & 3) * SLOT_FLOATS + lane;
#pragma unroll
      for (int u = 0; u < PHASE_T; ++u) {
        const float xv = xb[u * 64];           // ds_read_b32, free
        h1 = fmaxf(fmaf(w1, h1, xv), 0.0f);
        h2 = fmaxf(fmaf(w2, h2, h1), 0.0f);
        ob[u * 64] = h2;                       // ds_write_b32, free
      }
      __builtin_amdgcn_sched_barrier(0);
      asm volatile("s_waitcnt lgkmcnt(0)" ::: "memory");  // h2[p] visible
    }
    __builtin_amdgcn_s_barrier();              // final: releases out[NPHASE-1]
  } else {
    // ---------------- writers: wide decoupled stores ----------------
    const int w = wave - 2;                    // 0,1: t-half of each phase
    const int j = lane >> 4;
    const int i = lane & 15;

#define DRAIN(q)                                                              \
    do {                                                                      \
      const float* sb_ = ldso + ((q) & 3) * SLOT_FLOATS +                     \
                         (w * 16 + j) * 64 + i * 4;                           \
      float* gb_ = out + (size_t)((q) * PHASE_T + w * 16 + j) * BH +          \
                   cbase + i * 4;                                             \
      _Pragma("unroll")                                                       \
      for (int m_ = 0; m_ < 4; ++m_) {                                        \
        const float4 v_ = *(const float4*)(sb_ + m_ * 4 * 64);                \
        *(float4*)(gb_ + (size_t)m_ * 4 * BH) = v_;                           \
      }                                                                       \
    } while (0)

    for (int p = 0; p < NPHASE; ++p) {
      __builtin_amdgcn_s_barrier();            // B_p: out[p-1] complete
      __builtin_amdgcn_sched_barrier(0);
      if (p >= 1) DRAIN(p - 1);
    }
    __builtin_amdgcn_s_barrier();              // final
    __builtin_amdgcn_sched_barrier(0);
    DRAIN(NPHASE - 1);
#undef DRAIN
  }
}

extern "C" void kernel_launch(void* const* d_in, const int* in_sizes, int n_in,
                              void* d_out, int out_size, void* d_ws, size_t ws_size,
                              hipStream_t stream) {
  const float* x    = (const float*)d_in[0];
  const float* w_hh = (const float*)d_in[1];
  const float* h0   = (const float*)d_in[2];
  float* out        = (float*)d_out;

  dim3 grid(BH / 64);   // 256 blocks = 1 per CU
  dim3 block(256);      // w0: DMA in; w1: recurrence (LDS-only); w2-3: stores
  hipLaunchKernelGGL(indrnn_sw_kernel, grid, block, 0, stream,
                     x, w_hh, h0, out);
}